// Round 3
// baseline (629.682 us; speedup 1.0000x reference)
//
#include <hip/hip_runtime.h>

// y[b,s,n] = sum_k x[b,s,k] * (wq[n,k]*scale[blk]) + bias[n]
// M = 8192, N = 4096, K = 4096, fp32 in/out.
// R6: SINGLE fused kernel. The standalone cvt pass (stuck at 1.3-1.4 TB/s
// across 3 implementations, ~230us = half the total) is eliminated: A (x
// fp32->bf16) and B (wq fp32*scale->bf16) are reg-staged into LDS with the
// pack done in-register. LDS content, read path, MFMA order and rounding are
// bitwise-identical to R5 (absmax must stay 0.015625). ds_write side now
// swizzles directly (reg-staging can), replacing the inverse-source trick.

#define M_DIM 8192
#define N_DIM 4096
#define K_DIM 4096
#define K_TILES (K_DIM / 64)

typedef short s16x8 __attribute__((ext_vector_type(8)));   // 8 bf16 in 4 VGPRs
typedef float f32x4 __attribute__((ext_vector_type(4)));
typedef unsigned int u32x4 __attribute__((ext_vector_type(4)));

__device__ __forceinline__ unsigned int pack2_bf16(float a, float b) {
    unsigned int ua = __float_as_uint(a);
    unsigned int ub = __float_as_uint(b);
    unsigned int ra = ((ua + 0x7fffu + ((ua >> 16) & 1u)) >> 16) & 0xffffu;  // RNE
    unsigned int rb = (ub + 0x7fffu + ((ub >> 16) & 1u)) & 0xffff0000u;
    return ra | rb;
}

// ---- staging: unit = (row, k8) = 8 consecutive fp32 of one row ----
// thread t owns rows rT = t>>3 within each 64-row group it=0..3, k8 = t&7.
// chunk c covers row-groups {2c, 2c+1}: 4 float4 loads -> 2 ds_write_b128.
// LDS layout: [256 rows][64 k] bf16, 128 B/row, byte ^= (row&7)<<4 swizzle
// (row&7 == (t>>3)&7 since groups are 64-aligned) -- identical content to R5.

#define ISSUE_A(c) do {                                                        \
    const float* p0_ = X + (long)(m0 + (2*(c))*64   + rT) * K_DIM + kcN;       \
    const float* p1_ = X + (long)(m0 + (2*(c)+1)*64 + rT) * K_DIM + kcN;       \
    ga0 = *(const float4*)p0_; ga1 = *(const float4*)(p0_ + 4);                \
    ga2 = *(const float4*)p1_; ga3 = *(const float4*)(p1_ + 4);                \
  } while (0)

#define ISSUE_B(c) do {                                                        \
    const float* q0_ = Wq + (long)(n0 + (2*(c))*64   + rT) * K_DIM + kcN;      \
    const float* q1_ = Wq + (long)(n0 + (2*(c)+1)*64 + rT) * K_DIM + kcN;      \
    gb0 = *(const float4*)q0_; gb1 = *(const float4*)(q0_ + 4);                \
    gb2 = *(const float4*)q1_; gb3 = *(const float4*)(q1_ + 4);                \
  } while (0)

#define WRITE_A(c, nb) do {                                                    \
    u32x4 r0_, r1_;                                                            \
    r0_[0] = pack2_bf16(ga0.x, ga0.y); r0_[1] = pack2_bf16(ga0.z, ga0.w);      \
    r0_[2] = pack2_bf16(ga1.x, ga1.y); r0_[3] = pack2_bf16(ga1.z, ga1.w);      \
    r1_[0] = pack2_bf16(ga2.x, ga2.y); r1_[1] = pack2_bf16(ga2.z, ga2.w);      \
    r1_[2] = pack2_bf16(ga3.x, ga3.y); r1_[3] = pack2_bf16(ga3.z, ga3.w);      \
    *(u32x4*)(ldsA + (nb) + (2*(c))*8192   + wAddr) = r0_;                     \
    *(u32x4*)(ldsA + (nb) + (2*(c)+1)*8192 + wAddr) = r1_;                     \
  } while (0)

#define WRITE_B(c, nb, sA, sB) do {                                            \
    u32x4 r0_, r1_;                                                            \
    r0_[0] = pack2_bf16(gb0.x*(sA), gb0.y*(sA));                               \
    r0_[1] = pack2_bf16(gb0.z*(sA), gb0.w*(sA));                               \
    r0_[2] = pack2_bf16(gb1.x*(sA), gb1.y*(sA));                               \
    r0_[3] = pack2_bf16(gb1.z*(sA), gb1.w*(sA));                               \
    r1_[0] = pack2_bf16(gb2.x*(sB), gb2.y*(sB));                               \
    r1_[1] = pack2_bf16(gb2.z*(sB), gb2.w*(sB));                               \
    r1_[2] = pack2_bf16(gb3.x*(sB), gb3.y*(sB));                               \
    r1_[3] = pack2_bf16(gb3.z*(sB), gb3.w*(sB));                               \
    *(u32x4*)(ldsB + (nb) + (2*(c))*8192   + wAddr) = r0_;                     \
    *(u32x4*)(ldsB + (nb) + (2*(c)+1)*8192 + wAddr) = r1_;                     \
  } while (0)

#define READ_AF(dst, qm, bufb) do {                                            \
    _Pragma("unroll")                                                          \
    for (int i_ = 0; i_ < 4; ++i_) {                                           \
      dst[i_][0] = *(const s16x8*)(ldsA + (bufb) + aRowB + ((qm)*64 + i_*16)*128 + kk0); \
      dst[i_][1] = *(const s16x8*)(ldsA + (bufb) + aRowB + ((qm)*64 + i_*16)*128 + kk1); \
    }                                                                          \
  } while (0)

#define READ_BF(dst, qn, bufb) do {                                            \
    _Pragma("unroll")                                                          \
    for (int j_ = 0; j_ < 2; ++j_) {                                           \
      dst[j_][0] = *(const s16x8*)(ldsB + (bufb) + bRowB + ((qn)*32 + j_*16)*128 + kk0); \
      dst[j_][1] = *(const s16x8*)(ldsB + (bufb) + bRowB + ((qn)*32 + j_*16)*128 + kk1); \
    }                                                                          \
  } while (0)

#define MFMA32(qm, AF, BX, BY) do {                                            \
    __builtin_amdgcn_s_setprio(1);                                             \
    _Pragma("unroll")                                                          \
    for (int i_ = 0; i_ < 4; ++i_) {                                           \
      _Pragma("unroll")                                                        \
      for (int j_ = 0; j_ < 2; ++j_) {                                         \
        acc[(qm)*4+i_][j_] = __builtin_amdgcn_mfma_f32_16x16x32_bf16(          \
            AF[i_][0], BX[j_][0], acc[(qm)*4+i_][j_], 0, 0, 0);                \
        acc[(qm)*4+i_][j_] = __builtin_amdgcn_mfma_f32_16x16x32_bf16(          \
            AF[i_][1], BX[j_][1], acc[(qm)*4+i_][j_], 0, 0, 0);                \
      }                                                                        \
      _Pragma("unroll")                                                        \
      for (int j_ = 0; j_ < 2; ++j_) {                                         \
        acc[(qm)*4+i_][2+j_] = __builtin_amdgcn_mfma_f32_16x16x32_bf16(        \
            AF[i_][0], BY[j_][0], acc[(qm)*4+i_][2+j_], 0, 0, 0);              \
        acc[(qm)*4+i_][2+j_] = __builtin_amdgcn_mfma_f32_16x16x32_bf16(        \
            AF[i_][1], BY[j_][1], acc[(qm)*4+i_][2+j_], 0, 0, 0);              \
      }                                                                        \
    }                                                                          \
    __builtin_amdgcn_s_setprio(0);                                             \
  } while (0)

__global__ __launch_bounds__(512, 2) void gemm_fused_kernel(
    const float* __restrict__ X,    // M x K fp32
    const float* __restrict__ Wq,   // N x K fp32 (fp8 values)
    const float* __restrict__ Sc,   // N*K/128 scales
    const float* __restrict__ bias, // N
    float* __restrict__ C)          // M x N
{
    // [buf0: A 32KB | B 32KB][buf1: A 32KB | B 32KB] = 128 KiB
    __shared__ __align__(16) char lds[131072];
    char* ldsA = lds;
    char* ldsB = lds + 32768;

    const int t = threadIdx.x;
    const int l = t & 63;
    const int w = t >> 6;
    const int wr = w >> 2;          // 0..1 : wave row (128 rows each)
    const int wc = w & 3;           // 0..3 : wave col (64 cols each)

    int id = blockIdx.x;
    id = (id & 7) * 64 + (id >> 3);            // XCD-contiguous, bijective (512%8==0)
    const int m0 = (id >> 4) * 256;            // 32 m-tiles
    const int n0 = (id & 15) * 256;            // 16 n-tiles

    // ---- staging constants ----
    const int rT = t >> 3;                                  // 0..63
    const int wAddr = ((rT * 128 + (t & 7) * 16) ^ ((rT & 7) * 16));
    const int sIdx0 = (n0 + 0 * 64 + rT) * 32;              // scale row bases
    const int sIdx1 = (n0 + 1 * 64 + rT) * 32;
    const int sIdx2 = (n0 + 2 * 64 + rT) * 32;
    const int sIdx3 = (n0 + 3 * 64 + rT) * 32;

    // ---- ds_read fragment addressing (row = base+(l&15), k = ks*32+(l>>4)*8) ----
    const int aRowB = (wr * 128 + (l & 15)) * 128;   // bytes
    const int bRowB = (wc * 64  + (l & 15)) * 128;
    const int kx  = (l >> 4) * 16;
    const int sw  = (l & 7) * 16;                    // (row&7)<<4, lane-constant
    const int kk0 = kx ^ sw;
    const int kk1 = (64 + kx) ^ sw;

    f32x4 acc[8][4] = {};
    s16x8 af[4][2], bfX[2][2], bfY[2][2];
    float4 ga0, ga1, ga2, ga3, gb0, gb1, gb2, gb3;

    // ---- prologue: stage K-tile 0 into buf0 ----
    {
        const int kcN = (t & 7) * 8;                 // tile 0
        const float s0 = Sc[sIdx0], s1 = Sc[sIdx1];
        const float s2 = Sc[sIdx2], s3 = Sc[sIdx3];
        ISSUE_A(0); ISSUE_B(0);
        WRITE_A(0, 0); WRITE_B(0, 0, s0, s1);
        ISSUE_A(1); ISSUE_B(1);
        WRITE_A(1, 0); WRITE_B(1, 0, s2, s3);
        asm volatile("s_waitcnt lgkmcnt(0)" ::: "memory");
    }

    for (int kt = 0; kt < K_TILES - 1; ++kt) {
        const int cb = (kt & 1) * 65536;
        const int nb = 65536 - cb;
        const int kcN = (kt + 1) * 64 + (t & 7) * 8;
        // issue first chunks of kt+1 (flight: barrier + frag reads + MFMA32(0))
        ISSUE_A(0);
        ISSUE_B(0);
        const int sblk = (kt + 1) >> 1;
        const float s0 = Sc[sIdx0 + sblk], s1 = Sc[sIdx1 + sblk];
        const float s2 = Sc[sIdx2 + sblk], s3 = Sc[sIdx3 + sblk];
        // ---- phase 1 ----
        __builtin_amdgcn_s_barrier();
        __builtin_amdgcn_sched_barrier(0);
        READ_AF(af, 0, cb);
        READ_BF(bfX, 0, cb);
        READ_BF(bfY, 1, cb);
        MFMA32(0, af, bfX, bfY);
        WRITE_A(0, nb);          // vmcnt-waits ga (compiler), pack, 2 ds_write
        ISSUE_A(1);              // ga reuse orders this after the pack
        WRITE_B(0, nb, s0, s1);
        ISSUE_B(1);
        // ---- phase 2 ----
        __builtin_amdgcn_s_barrier();
        __builtin_amdgcn_sched_barrier(0);
        READ_AF(af, 1, cb);
        MFMA32(1, af, bfX, bfY);
        WRITE_A(1, nb);
        WRITE_B(1, nb, s2, s3);
        asm volatile("s_waitcnt lgkmcnt(0)" ::: "memory");   // writes visible
    }
    {   // last K-tile: compute only
        const int cb = ((K_TILES - 1) & 1) * 65536;
        __builtin_amdgcn_s_barrier();
        __builtin_amdgcn_sched_barrier(0);
        READ_AF(af, 0, cb);
        READ_BF(bfX, 0, cb);
        READ_BF(bfY, 1, cb);
        MFMA32(0, af, bfX, bfY);
        __builtin_amdgcn_s_barrier();
        __builtin_amdgcn_sched_barrier(0);
        READ_AF(af, 1, cb);
        MFMA32(1, af, bfX, bfY);
    }

    // epilogue: C/D layout row=(l>>4)*4+reg, col=l&15 (measured m89/m91)
    const int q4 = (l >> 4) * 4;
#pragma unroll
    for (int nf = 0; nf < 4; ++nf) {
        const int col = n0 + wc * 64 + nf * 16 + (l & 15);
        const float bv = bias[col];
#pragma unroll
        for (int mf = 0; mf < 8; ++mf) {
            const long row = m0 + wr * 128 + mf * 16 + q4;
#pragma unroll
            for (int r = 0; r < 4; ++r) {
                C[(row + r) * N_DIM + col] = acc[mf][nf][r] + bv;
            }
        }
    }
}

extern "C" void kernel_launch(void* const* d_in, const int* in_sizes, int n_in,
                              void* d_out, int out_size, void* d_ws, size_t ws_size,
                              hipStream_t stream) {
    const float* x      = (const float*)d_in[0];
    const float* wq     = (const float*)d_in[1];
    const float* scales = (const float*)d_in[2];
    const float* bias   = (const float*)d_in[3];
    float* out = (float*)d_out;

    gemm_fused_kernel<<<dim3(512), dim3(512), 0, stream>>>(
        x, wq, scales, bias, out);
}

// Round 4
// 491.442 us; speedup vs baseline: 1.2813x; 1.2813x over previous
//
#include <hip/hip_runtime.h>

// y[b,s,n] = sum_k x[b,s,k] * (wq[n,k]*scale[blk]) + bias[n]
// M = 8192, N = 4096, K = 4096, fp32 in/out.
// R7: revert R6's fusion (fixed harness overhead ~153us was misattributed to
// cvt; fused fp32 staging doubled FETCH and tanked MfmaUtil to 24%). Back to
// R5's two-kernel pipeline; GEMM now runs ONE barrier + ONE scheduling region
// per K-tile: the mid-tile barrier was provably redundant (ph1's vmcnt(4)+
// barrier already certifies the whole tile), so all 24 ds_read_b128 and all
// 64 MFMAs live in a single region the compiler can interleave with
// fine-grained lgkmcnt. Second half-pair staging hoisted for full-tile flight.

#define M_DIM 8192
#define N_DIM 4096
#define K_DIM 4096
#define K_TILES (K_DIM / 64)

typedef short s16x8 __attribute__((ext_vector_type(8)));   // 8 bf16 in 4 VGPRs
typedef float f32x4 __attribute__((ext_vector_type(4)));
typedef unsigned int u32x4 __attribute__((ext_vector_type(4)));

__device__ __forceinline__ unsigned int pack2_bf16(float a, float b) {
    unsigned int ua = __float_as_uint(a);
    unsigned int ub = __float_as_uint(b);
    unsigned int ra = ((ua + 0x7fffu + ((ua >> 16) & 1u)) >> 16) & 0xffffu;  // RNE
    unsigned int rb = (ub + 0x7fffu + ((ub >> 16) & 1u)) & 0xffff0000u;
    return ra | rb;
}

// ---- pre-pass: grid-stride, 2 float4 loads -> 1 16B store (unchanged R5) ----
__global__ __launch_bounds__(256) void cvt_fused_kernel(
    const float4* __restrict__ x, const float4* __restrict__ wq,
    const float* __restrict__ scales,
    u32x4* __restrict__ xo, u32x4* __restrict__ wo) {
    const int NX   = (M_DIM * K_DIM) / 8;               // 4194304
    const int NTOT = NX + (N_DIM * K_DIM) / 8;          // 6291456
    const int stride = gridDim.x * blockDim.x;          // 524288 -> 12 iters
    for (int u = blockIdx.x * blockDim.x + threadIdx.x; u < NTOT; u += stride) {
        if (u < NX) {
            const float4 a = x[2 * u];
            const float4 b = x[2 * u + 1];
            u32x4 r;
            r[0] = pack2_bf16(a.x, a.y); r[1] = pack2_bf16(a.z, a.w);
            r[2] = pack2_bf16(b.x, b.y); r[3] = pack2_bf16(b.z, b.w);
            xo[u] = r;
        } else {
            const int v = u - NX;
            const float s = scales[v >> 4];             // 16 units per 128-block
            float4 a = wq[2 * v];
            float4 b = wq[2 * v + 1];
            a.x *= s; a.y *= s; a.z *= s; a.w *= s;
            b.x *= s; b.y *= s; b.z *= s; b.w *= s;
            u32x4 r;
            r[0] = pack2_bf16(a.x, a.y); r[1] = pack2_bf16(a.z, a.w);
            r[2] = pack2_bf16(b.x, b.y); r[3] = pack2_bf16(b.z, b.w);
            wo[v] = r;
        }
    }
}

// ---- async 16B global -> LDS ----
__device__ __forceinline__ void async_copy16(const void* g, void* l) {
    __builtin_amdgcn_global_load_lds(
        (const __attribute__((address_space(1))) unsigned int*)g,
        (__attribute__((address_space(3))) unsigned int*)l,
        16, 0, 0);
}

// ---- GEMM: C[M,N] = A[M,K](bf16) * B[N,K]^T(bf16) + bias ----
// 256x256 tile, BK=64, 8 waves (2M x 4N), 512 thr, 128 KiB dbuf LDS.
// Per K-tile: stage {A0,B0}(kt+1); vmcnt(4); barrier  [whole tile kt certified:
// the 4 loads left in flight are exactly {A0,B0}(kt+1)]; then ONE region:
// 16 reads (af0,bfX,bfY) + stage {B1,A1}(kt+1) + MFMA32(qm0) + 8 reads (af1)
// + MFMA32(qm1). No mid-tile barrier. Race margin: any LDS region's overwrite
// lands >=1 tile-exec (~600cy) after the barrier releasing its readers; reads
// complete <=~150cy after it.
// LDS swizzle: byte ^= (row&7)<<4 on reads; staging keeps LDS dest linear and
// pre-swizzles the GLOBAL source column (both sides, same involution).

#define STAGE_A_HALF(h, ktt, bufb) do {                                        \
    const unsigned short* g_ = gA0 + (ktt) * 64 + (h) * (64 * K_DIM);          \
    async_copy16(g_,               ldsA + (bufb) + (h) * 8192 + aOff);         \
    async_copy16(g_ + 128 * K_DIM, ldsA + (bufb) + (h) * 8192 + 16384 + aOff); \
  } while (0)

#define STAGE_B_HALF(h, ktt, bufb) do {                                        \
    const unsigned short* g_ = gB0 + (ktt) * 64 + (h) * (32 * K_DIM);          \
    async_copy16(g_,               ldsB + (bufb) + (h) * 4096 + bOff);         \
    async_copy16(g_ + 128 * K_DIM, ldsB + (bufb) + (h) * 4096 + 16384 + bOff); \
  } while (0)

#define READ_AF(dst, qm, bufb) do {                                            \
    _Pragma("unroll")                                                          \
    for (int i_ = 0; i_ < 4; ++i_) {                                           \
      dst[i_][0] = *(const s16x8*)(ldsA + (bufb) + aRowB + ((qm)*64 + i_*16)*128 + kk0); \
      dst[i_][1] = *(const s16x8*)(ldsA + (bufb) + aRowB + ((qm)*64 + i_*16)*128 + kk1); \
    }                                                                          \
  } while (0)

#define READ_BF(dst, qn, bufb) do {                                            \
    _Pragma("unroll")                                                          \
    for (int j_ = 0; j_ < 2; ++j_) {                                           \
      dst[j_][0] = *(const s16x8*)(ldsB + (bufb) + bRowB + ((qn)*32 + j_*16)*128 + kk0); \
      dst[j_][1] = *(const s16x8*)(ldsB + (bufb) + bRowB + ((qn)*32 + j_*16)*128 + kk1); \
    }                                                                          \
  } while (0)

// 32 MFMAs for C-quadrant row qm. Per-accumulator k-order (ks0 then ks1,
// kt ascending) identical to R5 -> bitwise-identical output.
#define MFMA32(qm, AF, BX, BY) do {                                            \
    __builtin_amdgcn_s_setprio(1);                                             \
    _Pragma("unroll")                                                          \
    for (int i_ = 0; i_ < 4; ++i_) {                                           \
      _Pragma("unroll")                                                        \
      for (int j_ = 0; j_ < 2; ++j_) {                                         \
        acc[(qm)*4+i_][j_] = __builtin_amdgcn_mfma_f32_16x16x32_bf16(          \
            AF[i_][0], BX[j_][0], acc[(qm)*4+i_][j_], 0, 0, 0);                \
        acc[(qm)*4+i_][j_] = __builtin_amdgcn_mfma_f32_16x16x32_bf16(          \
            AF[i_][1], BX[j_][1], acc[(qm)*4+i_][j_], 0, 0, 0);                \
      }                                                                        \
      _Pragma("unroll")                                                        \
      for (int j_ = 0; j_ < 2; ++j_) {                                         \
        acc[(qm)*4+i_][2+j_] = __builtin_amdgcn_mfma_f32_16x16x32_bf16(        \
            AF[i_][0], BY[j_][0], acc[(qm)*4+i_][2+j_], 0, 0, 0);              \
        acc[(qm)*4+i_][2+j_] = __builtin_amdgcn_mfma_f32_16x16x32_bf16(        \
            AF[i_][1], BY[j_][1], acc[(qm)*4+i_][2+j_], 0, 0, 0);              \
      }                                                                        \
    }                                                                          \
    __builtin_amdgcn_s_setprio(0);                                             \
  } while (0)

__global__ __launch_bounds__(512, 2) void gemm_bt_kernel(
    const unsigned short* __restrict__ A,   // M x K bf16 bits
    const unsigned short* __restrict__ B,   // N x K bf16 bits
    const float* __restrict__ bias,         // N
    float* __restrict__ C)                  // M x N
{
    // [buf0: A 32KB | B 32KB][buf1: A 32KB | B 32KB] = 128 KiB
    __shared__ __align__(16) char lds[131072];
    char* ldsA = lds;
    char* ldsB = lds + 32768;

    const int t = threadIdx.x;
    const int l = t & 63;
    const int w = t >> 6;
    const int wr = w >> 2;          // 0..1 : wave row (128 rows each)
    const int wc = w & 3;           // 0..3 : wave col (64 cols each)

    int id = blockIdx.x;
    id = (id & 7) * 64 + (id >> 3);            // XCD-contiguous, bijective (512%8==0)
    const int m0 = (id >> 4) * 256;            // 32 m-tiles
    const int n0 = (id & 15) * 256;            // 16 n-tiles

    // ---- staging addresses (pre-swizzled global source, linear LDS dest) ----
    const int trow = t >> 3;                                // 0..63
    const int tcol = ((t & 7) * 8) ^ ((trow & 7) * 8);      // swizzled col (elems)
    const unsigned short* gA0 = A + (long)(m0 + trow) * K_DIM + tcol;
    const int brow = ((t >> 8) * 64) + ((t & 255) >> 3);    // brow&7 == trow&7
    const unsigned short* gB0 = B + (long)(n0 + brow) * K_DIM + tcol;
    const int aOff = t * 16;
    const int bOff = ((t >> 8) * 8192) + ((t & 255) * 16);

    // ---- ds_read fragment addressing (row = base+(l&15), k = ks*32+(l>>4)*8) ----
    const int aRowB = (wr * 128 + (l & 15)) * 128;   // bytes
    const int bRowB = (wc * 64  + (l & 15)) * 128;
    const int kx  = (l >> 4) * 16;
    const int sw  = (l & 7) * 16;                    // (row&7)<<4, lane-constant
    const int kk0 = kx ^ sw;
    const int kk1 = (64 + kx) ^ sw;

    f32x4 acc[8][4] = {};
    s16x8 af[4][2], bfX[2][2], bfY[2][2];

    // prologue: K-tile 0 into buf0 (8 loads)
    STAGE_A_HALF(0, 0, 0);
    STAGE_B_HALF(0, 0, 0);
    STAGE_B_HALF(1, 0, 0);
    STAGE_A_HALF(1, 0, 0);

    for (int kt = 0; kt < K_TILES - 1; ++kt) {
        const int cb = (kt & 1) * 65536;
        const int nb = 65536 - cb;
        // stage first half-pair of kt+1; vmcnt(4) leaves exactly these 4 loads
        // in flight -> everything tile kt needs is in LDS at the barrier.
        STAGE_A_HALF(0, kt + 1, nb);
        STAGE_B_HALF(0, kt + 1, nb);
        asm volatile("s_waitcnt vmcnt(4)" ::: "memory");
        __builtin_amdgcn_s_barrier();
        __builtin_amdgcn_sched_barrier(0);
        // ---- single scheduling region for the whole K-tile ----
        READ_AF(af, 0, cb);
        READ_BF(bfX, 0, cb);
        READ_BF(bfY, 1, cb);
        STAGE_B_HALF(1, kt + 1, nb);     // full-tile flight for second pair
        STAGE_A_HALF(1, kt + 1, nb);
        MFMA32(0, af, bfX, bfY);
        READ_AF(af, 1, cb);              // interleaves into qm0 MFMA tail
        MFMA32(1, af, bfX, bfY);
    }
    {   // last K-tile: drain all staging, compute
        const int cb = ((K_TILES - 1) & 1) * 65536;
        asm volatile("s_waitcnt vmcnt(0)" ::: "memory");
        __builtin_amdgcn_s_barrier();
        __builtin_amdgcn_sched_barrier(0);
        READ_AF(af, 0, cb);
        READ_BF(bfX, 0, cb);
        READ_BF(bfY, 1, cb);
        MFMA32(0, af, bfX, bfY);
        READ_AF(af, 1, cb);
        MFMA32(1, af, bfX, bfY);
    }

    // epilogue: C/D layout row=(l>>4)*4+reg, col=l&15 (measured m89/m91)
    const int q4 = (l >> 4) * 4;
#pragma unroll
    for (int nf = 0; nf < 4; ++nf) {
        const int col = n0 + wc * 64 + nf * 16 + (l & 15);
        const float bv = bias[col];
#pragma unroll
        for (int mf = 0; mf < 8; ++mf) {
            const long row = m0 + wr * 128 + mf * 16 + q4;
#pragma unroll
            for (int r = 0; r < 4; ++r) {
                C[(row + r) * N_DIM + col] = acc[mf][nf][r] + bv;
            }
        }
    }
}

extern "C" void kernel_launch(void* const* d_in, const int* in_sizes, int n_in,
                              void* d_out, int out_size, void* d_ws, size_t ws_size,
                              hipStream_t stream) {
    const float* x      = (const float*)d_in[0];
    const float* wq     = (const float*)d_in[1];
    const float* scales = (const float*)d_in[2];
    const float* bias   = (const float*)d_in[3];
    float* out = (float*)d_out;

    unsigned short* x_bf = (unsigned short*)d_ws;                 // 67.1 MB
    unsigned short* w_bf = x_bf + (size_t)M_DIM * K_DIM;          // 33.6 MB

    cvt_fused_kernel<<<2048, 256, 0, stream>>>(
        (const float4*)x, (const float4*)wq, scales,
        (u32x4*)x_bf, (u32x4*)w_bf);

    gemm_bt_kernel<<<dim3(512), dim3(512), 0, stream>>>(x_bf, w_bf, bias, out);
}